// Round 2
// baseline (211.456 us; speedup 1.0000x reference)
//
#include <hip/hip_runtime.h>

#define NL 100
#define BB 8
#define HH 1024
#define NPIX (1024 * 1024)
#define EPSF 1e-7f
#define NBLK 128          // stats blocks per batch (8 rows each) -- proven structure
#define LBK 64            // loss blocks per batch (16 rows each)
#define NLOSS (LBK * BB)  // 512 loss blocks

typedef float f4 __attribute__((ext_vector_type(4)));

// ws word offsets
#define OFF_ACC  0                                  // float loss accumulator
#define OFF_TKT  1                                  // u32 ticket
#define OFF_M8   8                                  // u32[BB*NPIX/4] packed u8 labels
#define OFF_PART (OFF_M8 + BB * (NPIX / 4))         // u32[5*BB*NL*NBLK], [v][b][l][blk]
#define WS_NEED  ((size_t)(OFF_PART + 5 * BB * NL * NBLK) * 4)

__device__ __forceinline__ int pidx(int v, int b, int l) {
    return ((v * BB + b) * NL + l) * NBLK;   // blk contiguous -> uint4 loads in K2
}

// K1: proven stats kernel (wave = 2 rows, packed cnt<<21|sx tables, one flush per
// 2 rows, block partials -> plain stores). Only changes vs the 179.8us version:
// partial layout is [v][b][l][blk], and block (0,0) zeroes the acc/ticket words.
__global__ __launch_bounds__(256) void k_stats(const int* __restrict__ mask,
                                               unsigned* __restrict__ wsu) {
    __shared__ unsigned s_cs[4][2][NL];   // per wave, per row: cnt<<21 | sum_x
    __shared__ unsigned s_mx[4][NL];
    __shared__ unsigned g_cnt[NL], g_sx[NL], g_sy[NL], g_mx[NL], g_my[NL];
    unsigned* part = wsu + OFF_PART;
    unsigned* m8   = wsu + OFF_M8;
    const int b    = blockIdx.y;
    const int blk  = blockIdx.x;
    const int wv   = threadIdx.x >> 6;
    const int lane = threadIdx.x & 63;
    if (blk == 0 && b == 0 && threadIdx.x == 0) {
        ((float*)wsu)[OFF_ACC] = 0.0f;     // visible to K2 via kernel boundary
        wsu[OFF_TKT] = 0u;
    }
    for (int i = threadIdx.x; i < NL; i += 256) {
        g_cnt[i] = 0u; g_sx[i] = 0u; g_sy[i] = 0u; g_mx[i] = 0u; g_my[i] = 0u;
    }
    for (int i = lane; i < 2 * NL; i += 64) s_cs[wv][0][i] = 0u;   // covers [0] and [1]
    for (int i = lane; i < NL; i += 64) s_mx[wv][i] = 0u;
    __syncthreads();

    const int4* m4  = (const int4*)(mask + (size_t)b * NPIX);
    unsigned*   m8b = m8 + (size_t)b * (NPIX / 4);
    const int y0 = blk * 8 + wv * 2;

    int4 R[2][4];
#pragma unroll
    for (int r = 0; r < 2; ++r)
#pragma unroll
        for (int it = 0; it < 4; ++it)
            R[r][it] = m4[(y0 + r) * 256 + it * 64 + lane];

#pragma unroll
    for (int r = 0; r < 2; ++r) {
        unsigned* tp = &s_cs[wv][r][0];
        unsigned* mp = &s_mx[wv][0];
        const int y = y0 + r;
#pragma unroll
        for (int it = 0; it < 4; ++it) {
            const int4 mv = R[r][it];
            const int c4 = it * 64 + lane;
            const unsigned v0 = (1u << 21) + (unsigned)(c4 << 2);
            atomicAdd(tp + mv.x, v0);      atomicMax(mp + mv.x, v0);
            atomicAdd(tp + mv.y, v0 + 1u); atomicMax(mp + mv.y, v0 + 1u);
            atomicAdd(tp + mv.z, v0 + 2u); atomicMax(mp + mv.z, v0 + 2u);
            atomicAdd(tp + mv.w, v0 + 3u); atomicMax(mp + mv.w, v0 + 3u);
            m8b[y * 256 + c4] = (unsigned)mv.x | ((unsigned)mv.y << 8) |
                                ((unsigned)mv.z << 16) | ((unsigned)mv.w << 24);
        }
    }
    // single flush for both rows of this wave (wave-private tables: no barrier)
    for (int e = lane; e < NL; e += 64) {
        const unsigned cs0 = s_cs[wv][0][e];
        const unsigned cs1 = s_cs[wv][1][e];
        const unsigned c0 = cs0 >> 21, c1 = cs1 >> 21;
        const unsigned cnt = c0 + c1;
        if (cnt) {
            atomicAdd(&g_cnt[e], cnt);
            atomicAdd(&g_sx[e], (cs0 & 0x1FFFFFu) + (cs1 & 0x1FFFFFu));
            atomicAdd(&g_sy[e], c0 * (unsigned)y0 + c1 * (unsigned)(y0 + 1));
            atomicMax(&g_my[e], c1 ? (unsigned)(y0 + 1) : (unsigned)y0);
            atomicMax(&g_mx[e], s_mx[wv][e] & 0x1FFFFFu);
        }
    }
    __syncthreads();
    for (int e = threadIdx.x; e < NL; e += 256) {
        part[pidx(0, b, e) + blk] = g_cnt[e];
        part[pidx(1, b, e) + blk] = g_sx[e];
        part[pidx(2, b, e) + blk] = g_sy[e];
        part[pidx(3, b, e) + blk] = g_mx[e];
        part[pidx(4, b, e) + blk] = g_my[e];
    }
}

// K2: fused final+loss+sum. grid(LBK, BB) x 256, 16 rows/block.
// Phase 1: every block redundantly reduces its batch's partials (L2-resident,
// uint4-vectorized) into an LDS table -- replaces k_final + 2 launch gaps.
// Phase 2: proven loss+gt body over 4 row-groups. Phase 3: acc+ticket finish.
__global__ __launch_bounds__(256, 2) void k_loss(const float* __restrict__ pred,
                                                 const float* __restrict__ ig,
                                                 unsigned* __restrict__ wsu,
                                                 float* __restrict__ out) {
    __shared__ unsigned s_st[5][NL];
    __shared__ unsigned s_c0[BB];
    __shared__ f4 s_tab[NL];
    __shared__ float s_red[4];
    const unsigned* part = wsu + OFF_PART;
    const unsigned* m8   = wsu + OFF_M8;
    const int b   = blockIdx.y;
    const int tid = threadIdx.x;

    if (tid < BB) s_c0[tid] = 0u;
    __syncthreads();
    // all-batch label-0 counts (for fg/bg denominators): 32 threads per batch
    {
        const int bb = tid >> 5, j = tid & 31;
        const uint4* p4 = (const uint4*)(part + pidx(0, bb, 0));
        const uint4 u = p4[j];
        atomicAdd(&s_c0[bb], u.x + u.y + u.z + u.w);
    }
    // 500 reduce tasks (v,l) for THIS batch: 32 uint4 loads each, blk-contiguous
    for (int t = tid; t < 5 * NL; t += 256) {
        const int v = t / NL;
        const int l = t - v * NL;
        const uint4* p4 = (const uint4*)(part + pidx(v, b, l));
        unsigned s = 0u, m = 0u;
#pragma unroll 8
        for (int k = 0; k < NBLK / 4; ++k) {
            const uint4 u = p4[k];
            s += u.x + u.y + u.z + u.w;
            m = max(max(m, u.x), max(u.y, max(u.z, u.w)));
        }
        s_st[v][l] = (v >= 3) ? m : s;
    }
    __syncthreads();
    if (tid < NL) {   // table entry (same math as proven k_final)
        const unsigned cnt = s_st[0][tid];
        const float sc = (float)(cnt ? cnt : 1u);
        const float xc = (float)s_st[1][tid] / sc;
        const float yc = (float)s_st[2][tid] / sc;
        float fmx = (float)s_st[3][tid] - xc; if (fmx < 0.0f) fmx = 0.0f;
        float fmy = (float)s_st[4][tid] - yc; if (fmy < 0.0f) fmy = 0.0f;
        f4 e;
        e.x = xc;
        e.y = yc;
        e.z = (fmx == 0.0f) ? 1.0f : 1.0f / fmx;
        e.w = (fmy == 0.0f) ? 1.0f : 1.0f / fmy;
        s_tab[tid] = e;
    }
    __syncthreads();
    float bgc = 0.0f;
#pragma unroll
    for (int i = 0; i < BB; ++i) bgc += (float)s_c0[i];
    const float n = (float)BB * (float)NPIX;
    const float inv_bg = 1.0f / (bgc + EPSF * n);
    const float inv_fg = 1.0f / ((n - bgc) + EPSF * n);

    const unsigned* m8b = m8 + (size_t)b * (NPIX / 4);
    const f4* ig4 = (const f4*)(ig + (size_t)b * NPIX);
    const f4* px4 = (const f4*)(pred + (size_t)(2 * b) * NPIX);
    const f4* py4 = (const f4*)(pred + (size_t)(2 * b + 1) * NPIX);
    f4* gx4 = (f4*)(out + 1 + (size_t)(2 * b) * NPIX);   // +4B misaligned: HW-ok (proven)
    f4* gy4 = (f4*)(out + 1 + (size_t)(2 * b + 1) * NPIX);

    float acc = 0.0f;
#pragma unroll
    for (int g = 0; g < 4; ++g) {        // 4 proven 4-row bodies = 16 rows/block
        const int base = (blockIdx.x * 4 + g) * 1024;
        unsigned M8[4]; f4 IV[4], PX[4], PY[4];
#pragma unroll
        for (int it = 0; it < 4; ++it) {
            const int i4 = base + it * 256 + tid;
            M8[it] = m8b[i4];
            IV[it] = __builtin_nontemporal_load(&ig4[i4]);
            PX[it] = __builtin_nontemporal_load(&px4[i4]);
            PY[it] = __builtin_nontemporal_load(&py4[i4]);
        }
#pragma unroll
        for (int it = 0; it < 4; ++it) {
            const int i4 = base + it * 256 + tid;
            const int p  = i4 << 2;
            const float x0 = (float)(p & (HH - 1));
            const float y  = (float)(p >> 10);
            const float* igs = (const float*)&IV[it];
            const float* pxs = (const float*)&PX[it];
            const float* pys = (const float*)&PY[it];
            f4 gxv, gyv;
            float* gxa = (float*)&gxv;
            float* gya = (float*)&gyv;
#pragma unroll
            for (int j = 0; j < 4; ++j) {
                const int m = (int)((M8[it] >> (8 * j)) & 255u);
                const f4 t = s_tab[m];
                const float fgf = (m != 0) ? 1.0f : 0.0f;
                const float gx = (x0 + (float)j - t.x) * t.z * fgf;
                const float gy = (y - t.y) * t.w * fgf;
                const float w  = ((m != 0) ? inv_fg : inv_bg) * igs[j];
                const float dx = pxs[j] - gx;
                const float dy = pys[j] - gy;
                const float ax = fabsf(dx), ay = fabsf(dy);
                acc += ((ax < 1.0f) ? 0.5f * dx * dx : ax - 0.5f) * w
                     + ((ay < 1.0f) ? 0.5f * dy * dy : ay - 0.5f) * w;
                gxa[j] = gx;
                gya[j] = gy;
            }
            __builtin_nontemporal_store(gxv, &gx4[i4]);
            __builtin_nontemporal_store(gyv, &gy4[i4]);
        }
    }
    // wave + block reduction, then acc+ticket finish (no dependence on out zeroing)
#pragma unroll
    for (int off = 32; off > 0; off >>= 1) acc += __shfl_down(acc, off, 64);
    const int lane = tid & 63, wv = tid >> 6;
    if (lane == 0) s_red[wv] = acc;
    __syncthreads();
    if (tid == 0) {
        const float s = s_red[0] + s_red[1] + s_red[2] + s_red[3];
        atomicAdd((float*)wsu + OFF_ACC, s);
        __threadfence();
        const unsigned old = atomicAdd(wsu + OFF_TKT, 1u);
        if (old == NLOSS - 1) {   // last block: every acc-add is ordered before us
            __threadfence();
            out[0] = atomicAdd((float*)wsu + OFF_ACC, 0.0f);
        }
    }
}

extern "C" void kernel_launch(void* const* d_in, const int* in_sizes, int n_in,
                              void* d_out, int out_size, void* d_ws, size_t ws_size,
                              hipStream_t stream) {
    const float* pred = (const float*)d_in[0];
    const int*   mask = (const int*)d_in[1];
    const float* ig   = (const float*)d_in[2];
    float* out = (float*)d_out;
    unsigned* wsu = (unsigned*)d_ws;

    k_stats<<<dim3(NBLK, BB), 256, 0, stream>>>(mask, wsu);
    k_loss<<<dim3(LBK, BB), 256, 0, stream>>>(pred, ig, wsu, out);
}